// Round 11
// baseline (1008.865 us; speedup 1.0000x reference)
//
#include <hip/hip_runtime.h>

// QuantizedLinear M=8192 K=4096 N=11008.
// r11: A bypasses LDS entirely (global->VGPR direct from tiled workspace; L1 absorbs the
// 4x wave-column reuse). LDS holds only B (3x32KB ring): per-tile LDS traffic drops
// 256KB -> 96KB (the inferred binding pipe across r2..r10's ~750us plateau).
// One barrier + one vmcnt(12) per K-tile; A-readiness via compiler auto-waits.
// Block 256x256, 8 waves 2Mx4N, wave-tile 128x64, mfma_f32_32x32x16_f16.

#define K_DIM 4096
#define N_DIM 11008
#define M_DIM 8192
#define NT_K 64             // K_DIM / 64
#define TILE_BYTES 2097152  // per 256-row stripe: 64 ktiles * 32KB

typedef _Float16 f16;
typedef _Float16 f16x8 __attribute__((ext_vector_type(8)));
typedef float f32x16 __attribute__((ext_vector_type(16)));
typedef float fv4 __attribute__((ext_vector_type(4)));
typedef int iv4 __attribute__((ext_vector_type(4)));

__device__ __forceinline__ void gload16(const void* g, void* lds) {
  __builtin_amdgcn_global_load_lds(
      (__attribute__((address_space(1))) void*)g,
      (__attribute__((address_space(3))) void*)lds,
      16, 0, 0);
}

// fused prepass into tiled layout (unchanged from r9, passed).
// flat 16B-position i: [5:0]=lane, [9:6]=F, [10]=kk, [16:11]=t, [..:17]=stripe.
// row = stripe*256 + (F>>1)*32 + (lane&31); k = t*64 + kk*32 + (F&1)*16 + (lane>>5)*8.
__global__ __launch_bounds__(256) void prep_kernel(const float* __restrict__ x,
                                                   f16* __restrict__ xo, int n16x,
                                                   const int* __restrict__ q,
                                                   const float* __restrict__ amax,
                                                   f16* __restrict__ wo, int n16w) {
  int i = blockIdx.x * blockDim.x + threadIdx.x;
  if (i < n16x) {
    const int lam = i & 63;
    const int F = (i >> 6) & 15;
    const int kk = (i >> 10) & 1;
    const int t = (i >> 11) & 63;
    const int mt = i >> 17;
    const int row = mt * 256 + ((F >> 1) << 5) + (lam & 31);
    const int kc = t * 64 + (kk << 5) + ((F & 1) << 4) + ((lam >> 5) << 3);
    const fv4* src = (const fv4*)(x + (size_t)row * K_DIM + kc);
    fv4 a = __builtin_nontemporal_load(src);
    fv4 b = __builtin_nontemporal_load(src + 1);
    f16x8 o;
    o[0] = (f16)a.x; o[1] = (f16)a.y; o[2] = (f16)a.z; o[3] = (f16)a.w;
    o[4] = (f16)b.x; o[5] = (f16)b.y; o[6] = (f16)b.z; o[7] = (f16)b.w;
    *(f16x8*)(xo + (size_t)i * 8) = o;
  } else {
    int j = i - n16x;
    if (j >= n16w) return;
    const int lam = j & 63;
    const int F = (j >> 6) & 15;
    const int kk = (j >> 10) & 1;
    const int t = (j >> 11) & 63;
    const int nt = j >> 17;
    const int row = nt * 256 + ((F >> 1) << 5) + (lam & 31);
    const int kc = t * 64 + (kk << 5) + ((F & 1) << 4) + ((lam >> 5) << 3);
    const size_t base = (size_t)row * K_DIM + kc;
    const iv4* src = (const iv4*)(q + base);
    iv4 a = __builtin_nontemporal_load(src);
    iv4 b = __builtin_nontemporal_load(src + 1);
    float s = amax[base >> 6] * (1.0f / 7.0f);
    f16x8 o;
    o[0] = (f16)((float)a.x * s); o[1] = (f16)((float)a.y * s);
    o[2] = (f16)((float)a.z * s); o[3] = (f16)((float)a.w * s);
    o[4] = (f16)((float)b.x * s); o[5] = (f16)((float)b.y * s);
    o[6] = (f16)((float)b.z * s); o[7] = (f16)((float)b.w * s);
    *(f16x8*)(wo + (size_t)j * 8) = o;
  }
}

// A: loaded per-slab straight to VGPR. chunk u = mf*2+ks; addr = stripe + t*32768 + kk*16384
//   + (wr*8 + u)*1024 + l*16 — contiguous 1KB lane-linear blocks (perfectly coalesced).
// B: LDS ring 3 x 32KB; ktile = 32 chunks of 1KB ([kk][F][lane][16B], F=colblk*2+ks).
//   Wave w stages chunks {w, w+8} (h=0) and {w+16, w+24} (h=1); reads chunks wc*4+v (v=nf*2+ks).
__global__ __launch_bounds__(512, 2) void gemm_f16_bt(const f16* __restrict__ A,
                                                      const f16* __restrict__ B,
                                                      const float* __restrict__ bias,
                                                      float* __restrict__ C) {
  __shared__ __align__(16) char lds[98304];

  const int tid = threadIdx.x;
  const int w = tid >> 6;
  const int l = tid & 63;
  const int wr = w >> 2;  // 0..1 : 128 M-rows each
  const int wc = w & 3;   // 0..3 : 64 N-cols each

  // bijective XCD swizzle: nwg = 1376 = 8 * 172
  const int wg = blockIdx.x;
  const int swz = (wg & 7) * 172 + (wg >> 3);
  const int mt = swz / 43;
  const int nt = swz % 43;
  const int m0 = mt * 256;
  const int n0 = nt * 256;

  const char* Astripe = (const char*)A + (size_t)mt * TILE_BYTES + (wr << 13) + (l << 4);
  const char* Bstage = (const char*)B + (size_t)nt * TILE_BYTES + (w << 10) + (l << 4);
  char* ldsc = (char*)lds;
  const int boff = (wc << 12) + (l << 4);

#define LOAD_A(dst, tt, kk)                                            \
  {                                                                    \
    const char* s_ = Astripe + (size_t)(tt) * 32768 + ((kk) << 14);    \
    _Pragma("unroll") for (int u = 0; u < 8; ++u)                      \
        dst[u] = *(const f16x8*)(s_ + (u << 10));                      \
  }
#define STAGE_B2(slot, tt, h)                                 \
  {                                                           \
    const char* s_ = Bstage + (size_t)(tt) * 32768 + ((h) << 14); \
    char* d_ = ldsc + (slot) + ((h) << 14) + (w << 10);       \
    gload16(s_, d_);                                          \
    gload16(s_ + 8192, d_ + 8192);                            \
  }
#define READ_B(dst, slot, kk)                                   \
  {                                                             \
    const char* p_ = ldsc + (slot) + ((kk) << 14) + boff;       \
    _Pragma("unroll") for (int v = 0; v < 4; ++v)               \
        dst[v] = *(const f16x8*)(p_ + (v << 10));               \
  }
#define MFMA_SLAB(a, b)                                                     \
  __builtin_amdgcn_s_setprio(1);                                            \
  _Pragma("unroll") for (int ks = 0; ks < 2; ++ks)                          \
      _Pragma("unroll") for (int mf = 0; mf < 4; ++mf)                      \
          _Pragma("unroll") for (int nf = 0; nf < 2; ++nf)                  \
              acc[mf][nf] = __builtin_amdgcn_mfma_f32_32x32x16_f16(         \
                  a[mf * 2 + ks], b[nf * 2 + ks], acc[mf][nf], 0, 0, 0);    \
  __builtin_amdgcn_s_setprio(0);

  f32x16 acc[4][2];
#pragma unroll
  for (int i = 0; i < 4; ++i)
#pragma unroll
    for (int j = 0; j < 2; ++j) acc[i][j] = (f32x16)0.f;

  f16x8 aX[8], aY[8];   // kk0 / kk1 slab buffers
  f16x8 bf0[4], bf1[4];

  // prologue: stage B0 (4 DMA), B1 (4 DMA), load A(0,kk0); full drain once (order-proof)
  STAGE_B2(0, 0, 0);
  STAGE_B2(0, 0, 1);
  STAGE_B2(32768, 1, 0);
  STAGE_B2(32768, 1, 1);
  LOAD_A(aX, 0, 0);
  asm volatile("s_waitcnt vmcnt(0)" ::: "memory");
  __builtin_amdgcn_s_barrier();

  int bCur = 0;       // slot of tile t
  int bStg = 65536;   // stage slot for tile t+2
  for (int t = 0; t < NT_K; ++t) {
    const int tA = (t + 1 < NT_K) ? (t + 1) : (NT_K - 1);
    const int tS = (t + 2 < NT_K) ? (t + 2) : (NT_K - 1);
    const int bNxt = (bCur == 65536) ? 0 : bCur + 32768;

    LOAD_A(aY, t, 1);          // A(t,kk1) -> regs (hides under kk0 phase)
    STAGE_B2(bStg, tS, 0);     // B(t+2) first half -> free slot
    READ_B(bf0, bCur, 0);
    MFMA_SLAB(aX, bf0);        // compiler emits counted vmcnt for aX, lgkmcnt for bf0

    LOAD_A(aX, tA, 0);         // A(t+1,kk0) -> regs (hides under kk1 phase + barrier)
    STAGE_B2(bStg, tS, 1);     // B(t+2) second half
    READ_B(bf1, bCur, 1);
    MFMA_SLAB(aY, bf1);

    // all t-1 issues (incl. B(t+1) stages) are confirmed transitively by the aY auto-wait;
    // vmcnt(12) pins the invariant explicitly (keeps only this tile's 12 still-wanted loads).
    asm volatile("s_waitcnt vmcnt(12)" ::: "memory");
    __builtin_amdgcn_s_barrier();

    bCur = bNxt;
    bStg = (bStg == 65536) ? 0 : bStg + 32768;
  }

  // epilogue: 32x32 C/D layout col = lane&31, row = (reg&3) + 8*(reg>>2) + 4*(lane>>5)
  const int l31 = l & 31;
  const int rbase = 4 * (l >> 5);
  float bv[2];
#pragma unroll
  for (int nf = 0; nf < 2; ++nf) bv[nf] = bias[n0 + wc * 64 + nf * 32 + l31];
#pragma unroll
  for (int mf = 0; mf < 4; ++mf) {
#pragma unroll
    for (int nf = 0; nf < 2; ++nf) {
      const size_t col = n0 + wc * 64 + nf * 32 + l31;
#pragma unroll
      for (int qd = 0; qd < 4; ++qd) {
#pragma unroll
        for (int j = 0; j < 4; ++j) {
          const int row = m0 + wr * 128 + mf * 32 + rbase + 8 * qd + j;
          __builtin_nontemporal_store(acc[mf][nf][qd * 4 + j] + bv[nf],
                                      &C[(size_t)row * N_DIM + col]);
        }
      }
    }
  }
#undef LOAD_A
#undef STAGE_B2
#undef READ_B
#undef MFMA_SLAB
}

extern "C" void kernel_launch(void* const* d_in, const int* in_sizes, int n_in,
                              void* d_out, int out_size, void* d_ws, size_t ws_size,
                              hipStream_t stream) {
  const float* x = (const float*)d_in[0];
  const int* wq = (const int*)d_in[1];
  const float* amax = (const float*)d_in[2];
  const float* bias = (const float*)d_in[3];
  float* out = (float*)d_out;

  f16* Xh = (f16*)d_ws;                                       // 64 MB, tiled
  f16* Wh = (f16*)((char*)d_ws + (size_t)M_DIM * K_DIM * 2);  // 90.25 MB, tiled

  {
    int n16x = M_DIM * K_DIM / 8;  // 4,194,304
    int n16w = N_DIM * K_DIM / 8;  // 5,636,096
    int nthr = n16x + n16w;
    prep_kernel<<<(nthr + 255) / 256, 256, 0, stream>>>(x, Xh, n16x, wq, amax, Wh, n16w);
  }
  {
    dim3 grid((M_DIM / 256) * (N_DIM / 256));  // 32*43 = 1376
    gemm_f16_bt<<<grid, 512, 0, stream>>>(Xh, Wh, bias, out);
  }
}

// Round 12
// 884.646 us; speedup vs baseline: 1.1404x; 1.1404x over previous
//
#include <hip/hip_runtime.h>

// QuantizedLinear M=8192 K=4096 N=11008.
// r12: TWO BLOCKS PER CU. Model (validated on r5+r11): per-tile wall = MFMA + LDS traffic,
// serialized, because both waves/SIMD are in the same barrier-locked block. Fix: 256x128
// block, 4 waves, wave-tile 128x64 (r9/r10-proven datapath), BK=32, 3x24KB LDS ring = 72KB
// -> 2 independent blocks co-resident; one block's LDS/barrier drain overlaps the other's
// MFMA. Tiled workspace (lane-linear LDS, 0 conflicts), r9 skeleton schedule, vmcnt(6)/tile.

#define K_DIM 4096
#define N_DIM 11008
#define M_DIM 8192
#define NT 128               // K tiles of 32
#define A_STRIPE 2097152     // 128 ktiles * 16KB (256 rows x 32 k)
#define B_STRIPE 1048576     // 128 ktiles * 8KB  (128 rows x 32 k)
#define SLOT 24576           // LDS slot: A 16KB + B 8KB
#define B_OFF 16384

typedef _Float16 f16;
typedef _Float16 f16x8 __attribute__((ext_vector_type(8)));
typedef float f32x16 __attribute__((ext_vector_type(16)));
typedef float fv4 __attribute__((ext_vector_type(4)));
typedef int iv4 __attribute__((ext_vector_type(4)));

__device__ __forceinline__ void gload16(const void* g, void* lds) {
  __builtin_amdgcn_global_load_lds(
      (__attribute__((address_space(1))) void*)g,
      (__attribute__((address_space(3))) void*)lds,
      16, 0, 0);
}

// fused prepass into BK=32 tiled layouts.
// A 16B-pos i: [5:0]=lane, [9:6]=F(16), [16:10]=t(128), [..:17]=mt(32).
//   row = mt*256 + (F>>1)*32 + (l&31); k = t*32 + (F&1)*16 + (l>>5)*8.
// B 16B-pos j: [5:0]=lane, [8:6]=F(8), [15:9]=t(128), [..:16]=nt(86).
//   row = nt*128 + (F>>1)*32 + (l&31); k = t*32 + (F&1)*16 + (l>>5)*8.
__global__ __launch_bounds__(256) void prep_kernel(const float* __restrict__ x,
                                                   f16* __restrict__ xo, int n16x,
                                                   const int* __restrict__ q,
                                                   const float* __restrict__ amax,
                                                   f16* __restrict__ wo, int n16w) {
  int i = blockIdx.x * blockDim.x + threadIdx.x;
  if (i < n16x) {
    const int lam = i & 63;
    const int F = (i >> 6) & 15;
    const int t = (i >> 10) & 127;
    const int mt = i >> 17;
    const int row = mt * 256 + ((F >> 1) << 5) + (lam & 31);
    const int kc = t * 32 + ((F & 1) << 4) + ((lam >> 5) << 3);
    const fv4* src = (const fv4*)(x + (size_t)row * K_DIM + kc);
    fv4 a = __builtin_nontemporal_load(src);
    fv4 b = __builtin_nontemporal_load(src + 1);
    f16x8 o;
    o[0] = (f16)a.x; o[1] = (f16)a.y; o[2] = (f16)a.z; o[3] = (f16)a.w;
    o[4] = (f16)b.x; o[5] = (f16)b.y; o[6] = (f16)b.z; o[7] = (f16)b.w;
    *(f16x8*)(xo + (size_t)i * 8) = o;
  } else {
    int j = i - n16x;
    if (j >= n16w) return;
    const int lam = j & 63;
    const int F = (j >> 6) & 7;
    const int t = (j >> 9) & 127;
    const int nt = j >> 16;
    const int row = nt * 128 + ((F >> 1) << 5) + (lam & 31);
    const int kc = t * 32 + ((F & 1) << 4) + ((lam >> 5) << 3);
    const size_t base = (size_t)row * K_DIM + kc;
    const iv4* src = (const iv4*)(q + base);
    iv4 a = __builtin_nontemporal_load(src);
    iv4 b = __builtin_nontemporal_load(src + 1);
    float s = amax[base >> 6] * (1.0f / 7.0f);
    f16x8 o;
    o[0] = (f16)((float)a.x * s); o[1] = (f16)((float)a.y * s);
    o[2] = (f16)((float)a.z * s); o[3] = (f16)((float)a.w * s);
    o[4] = (f16)((float)b.x * s); o[5] = (f16)((float)b.y * s);
    o[6] = (f16)((float)b.z * s); o[7] = (f16)((float)b.w * s);
    *(f16x8*)(wo + (size_t)j * 8) = o;
  }
}

// GEMM: 256x128 block tile, 4 waves (wr=w>>1 M-half, wc=w&1 N-half), wave 128x64.
// LDS ring slots {0,24576,49152}: [A 16 chunks][B 8 chunks] of 1KB, lane-linear.
// Per tile: read A 8 + B 4 b128; stage tile t+2 (6 gloads: A chunks w+4u, B chunks w+4v);
// barrier; lgkmcnt(0); 16x mfma_32x32x16; vmcnt(6); barrier.
__global__ __launch_bounds__(256, 2) void gemm_f16_bt(const f16* __restrict__ A,
                                                      const f16* __restrict__ B,
                                                      const float* __restrict__ bias,
                                                      float* __restrict__ C) {
  __shared__ __align__(16) char lds[73728];

  const int tid = threadIdx.x;
  const int w = tid >> 6;
  const int l = tid & 63;
  const int wr = w >> 1;  // 0..1 : 128 M-rows each
  const int wc = w & 1;   // 0..1 : 64 N-cols each

  // bijective XCD swizzle: nwg = 2752 = 8 * 344 ; mt-major within XCD chunk (A L2 reuse)
  const int wg = blockIdx.x;
  const int swz = (wg & 7) * 344 + (wg >> 3);
  const int mt = swz / 86;    // 0..31
  const int ntile = swz % 86; // 0..85
  const int m0 = mt * 256;
  const int n0 = ntile * 128;

  const char* Aw = (const char*)A + (size_t)mt * A_STRIPE + (w << 10) + (l << 4);
  const char* Bw = (const char*)B + (size_t)ntile * B_STRIPE + (w << 10) + (l << 4);
  char* ldsc = (char*)lds;

  const int aoff = (wr << 13) + (l << 4);           // A read base within slot
  const int boff = B_OFF + (wc << 12) + (l << 4);   // B read base within slot

#define STAGE(slot, tt)                                            \
  {                                                                \
    const char* sa_ = Aw + (size_t)(tt) * 16384;                   \
    char* da_ = ldsc + (slot) + (w << 10);                         \
    _Pragma("unroll") for (int u = 0; u < 4; ++u)                  \
        gload16(sa_ + (u << 12), da_ + (u << 12));                 \
    const char* sb_ = Bw + (size_t)(tt) * 8192;                    \
    char* db_ = ldsc + (slot) + B_OFF + (w << 10);                 \
    _Pragma("unroll") for (int v = 0; v < 2; ++v)                  \
        gload16(sb_ + (v << 12), db_ + (v << 12));                 \
  }

  f32x16 acc[4][2];
#pragma unroll
  for (int i = 0; i < 4; ++i)
#pragma unroll
    for (int j = 0; j < 2; ++j) acc[i][j] = (f32x16)0.f;

  // prologue: stage tiles 0,1 ; vmcnt(6) confirms tile 0
  STAGE(0, 0);
  STAGE(SLOT, 1);
  asm volatile("s_waitcnt vmcnt(6)" ::: "memory");
  __builtin_amdgcn_s_barrier();

  int s0 = 0, s1 = SLOT, s2 = 2 * SLOT;  // slots of tiles t, t+1, t+2

  for (int t = 0; t < NT; ++t) {
    const int tS = (t + 2 < NT) ? (t + 2) : (NT - 1);

    f16x8 af[8], bf[4];
#pragma unroll
    for (int u = 0; u < 8; ++u)
      af[u] = *(const f16x8*)(ldsc + s0 + aoff + (u << 10));
#pragma unroll
    for (int v = 0; v < 4; ++v)
      bf[v] = *(const f16x8*)(ldsc + s0 + boff + (v << 10));

    STAGE(s2, tS);

    __builtin_amdgcn_s_barrier();
    asm volatile("s_waitcnt lgkmcnt(0)" ::: "memory");
    __builtin_amdgcn_sched_barrier(0);  // rule #18: pin MFMA below the wait
    __builtin_amdgcn_s_setprio(1);
#pragma unroll
    for (int ks = 0; ks < 2; ++ks)
#pragma unroll
      for (int mf = 0; mf < 4; ++mf)
#pragma unroll
        for (int nf = 0; nf < 2; ++nf)
          acc[mf][nf] = __builtin_amdgcn_mfma_f32_32x32x16_f16(
              af[mf * 2 + ks], bf[nf * 2 + ks], acc[mf][nf], 0, 0, 0);
    __builtin_amdgcn_s_setprio(0);
    asm volatile("s_waitcnt vmcnt(6)" ::: "memory");  // confirms tile t+1
    __builtin_amdgcn_s_barrier();

    const int tmp = s0; s0 = s1; s1 = s2; s2 = tmp;
  }

  // epilogue: 32x32 C/D layout col = lane&31, row = (reg&3) + 8*(reg>>2) + 4*(lane>>5)
  const int l31 = l & 31;
  const int rbase = 4 * (l >> 5);
  float bv[2];
#pragma unroll
  for (int nf = 0; nf < 2; ++nf) bv[nf] = bias[n0 + wc * 64 + nf * 32 + l31];
#pragma unroll
  for (int mf = 0; mf < 4; ++mf) {
#pragma unroll
    for (int nf = 0; nf < 2; ++nf) {
      const size_t col = n0 + wc * 64 + nf * 32 + l31;
#pragma unroll
      for (int qd = 0; qd < 4; ++qd) {
#pragma unroll
        for (int j = 0; j < 4; ++j) {
          const int row = m0 + wr * 128 + mf * 32 + rbase + 8 * qd + j;
          __builtin_nontemporal_store(acc[mf][nf][qd * 4 + j] + bv[nf],
                                      &C[(size_t)row * N_DIM + col]);
        }
      }
    }
  }
#undef STAGE
}

extern "C" void kernel_launch(void* const* d_in, const int* in_sizes, int n_in,
                              void* d_out, int out_size, void* d_ws, size_t ws_size,
                              hipStream_t stream) {
  const float* x = (const float*)d_in[0];
  const int* wq = (const int*)d_in[1];
  const float* amax = (const float*)d_in[2];
  const float* bias = (const float*)d_in[3];
  float* out = (float*)d_out;

  f16* Xh = (f16*)d_ws;                                       // 64 MB, tiled BK=32
  f16* Wh = (f16*)((char*)d_ws + (size_t)M_DIM * K_DIM * 2);  // 90.25 MB, tiled BK=32

  {
    int n16x = M_DIM * K_DIM / 8;  // 4,194,304
    int n16w = N_DIM * K_DIM / 8;  // 5,636,096
    int nthr = n16x + n16w;
    prep_kernel<<<(nthr + 255) / 256, 256, 0, stream>>>(x, Xh, n16x, wq, amax, Wh, n16w);
  }
  {
    dim3 grid((M_DIM / 256) * (N_DIM / 128));  // 32*86 = 2752
    gemm_f16_bt<<<grid, 256, 0, stream>>>(Xh, Wh, bias, out);
  }
}